// Round 8
// baseline (237.245 us; speedup 1.0000x reference)
//
#include <hip/hip_runtime.h>
#include <hip/hip_bf16.h>

#define NN 2048
#define FF 64
#define NH 8
#define BDIM 4
#define BH 32        // BDIM*NH

typedef __attribute__((ext_vector_type(8))) short short8;
typedef __attribute__((ext_vector_type(4))) float floatx4;
typedef __attribute__((ext_vector_type(4))) unsigned uint4v;
typedef __attribute__((ext_vector_type(2))) unsigned long long u64x2;

__device__ __forceinline__ float LDIN(const void* p, size_t i, int b16) {
    return b16 ? __bfloat162float(((const __hip_bfloat16*)p)[i]) : ((const float*)p)[i];
}
__device__ __forceinline__ unsigned packhi(float f0, float f1) {
    return __builtin_amdgcn_perm(__float_as_uint(f1), __float_as_uint(f0), 0x07060302);
}
__device__ __forceinline__ float hitrunc(float x) {
    return __uint_as_float(__float_as_uint(x) & 0xFFFF0000u);
}
// XOR-swizzled LDS index (stride 64 shorts, 8-short groups). col must be 4-aligned.
__device__ __forceinline__ int SWZ(int row, int col) {
    return row * 64 + ((((col >> 3) ^ (row & 7)) << 3) | (col & 7));
}
__device__ __forceinline__ float fast_tanh(float v) {
    float ex = __expf(2.0f * v);
    return 1.0f - 2.0f * __builtin_amdgcn_rcpf(ex + 1.0f);
}
__device__ __forceinline__ ushort bf16bits(float v) {
    __hip_bfloat16 b = __float2bfloat16(v);
    return __builtin_bit_cast(ushort, b);
}
__device__ __forceinline__ float bf2f(ushort u) {
    return __uint_as_float((unsigned)u << 16);
}
__device__ __forceinline__ int sniff_b16(const void* h) {
    unsigned word = ((const unsigned*)h)[threadIdx.x & 63];
    unsigned lowexp = (word >> 7) & 0xFFu;
    bool plaus = (lowexp >= 96u && lowexp <= 159u);
    unsigned long long m = __ballot(plaus);
    return (__popcll(m) >= 48) ? 1 : 0;
}
// monotone float->unsigned map: f0 < f1  <=>  mkey(f0) < mkey(f1)
__device__ __forceinline__ unsigned mkey(float f) {
    unsigned u = __float_as_uint(f);
    return (u & 0x80000000u) ? ~u : (u | 0x80000000u);
}

// ---- Kernel 1: MFMA GEMM hp=h@w; bf16 hp rows + s/d/r per row ---------------
// grid 1024 = 32 bh x 32 row-tiles (64 rows each). 256 thr = 4 waves.
// w fragments loaded straight to registers (w is tiny and L2-hot).
__global__ __launch_bounds__(256) void k_proj(
    const void* __restrict__ h, const void* __restrict__ w,
    const void* __restrict__ asrc, const void* __restrict__ adst,
    ushort* __restrict__ hpB, float* __restrict__ sArr, float* __restrict__ dArr,
    float* __restrict__ rArr)
{
    const int t  = threadIdx.x;
    const int rt = blockIdx.x & 31;
    const int hd = (blockIdx.x >> 5) & 7;
    const int b  = blockIdx.x >> 8;
    const int bh = b * NH + hd;
    const int r0 = rt * 64;
    const int lane = t & 63, wv = t >> 6;
    const int ml = lane & 15, q = lane >> 4;

    __shared__ ushort aHi[4096];
    __shared__ ushort aLo[4096];
    __shared__ ushort sB[64 * 72];    // bf16 out staging, 16B-aligned rows
    __shared__ int sb16;
    if (t < 64) { int f = sniff_b16(h); if (t == 0) sb16 = f; }
    __syncthreads();
    const int b16 = sb16;

    short8 bhf[4][2], blf[4][2];
    if (b16) {
        const ushort* wp = (const ushort*)w + (size_t)hd * FF * FF;
#pragma unroll
        for (int nt = 0; nt < 4; ++nt)
#pragma unroll
            for (int kc = 0; kc < 2; ++kc) {
                ushort v[8];
#pragma unroll
                for (int j = 0; j < 8; ++j)
                    v[j] = wp[(kc * 32 + q * 8 + j) * FF + nt * 16 + ml];
                bhf[nt][kc] = *(short8*)v;
            }
    } else {
        const float* wp = (const float*)w + (size_t)hd * FF * FF;
#pragma unroll
        for (int nt = 0; nt < 4; ++nt)
#pragma unroll
            for (int kc = 0; kc < 2; ++kc) {
                float x[8];
#pragma unroll
                for (int j = 0; j < 8; ++j)
                    x[j] = wp[(kc * 32 + q * 8 + j) * FF + nt * 16 + ml];
                uint4v hv = { packhi(x[0], x[1]), packhi(x[2], x[3]),
                              packhi(x[4], x[5]), packhi(x[6], x[7]) };
                uint4v lv = { packhi(x[0] - hitrunc(x[0]), x[1] - hitrunc(x[1])),
                              packhi(x[2] - hitrunc(x[2]), x[3] - hitrunc(x[3])),
                              packhi(x[4] - hitrunc(x[4]), x[5] - hitrunc(x[5])),
                              packhi(x[6] - hitrunc(x[6]), x[7] - hitrunc(x[7])) };
                bhf[nt][kc] = __builtin_bit_cast(short8, hv);
                blf[nt][kc] = __builtin_bit_cast(short8, lv);
            }
    }

    float aS[4], aD[4];
#pragma unroll
    for (int nt = 0; nt < 4; ++nt) {
        aS[nt] = LDIN(asrc, hd * FF + nt * 16 + ml, b16);
        aD[nt] = LDIN(adst, hd * FF + nt * 16 + ml, b16);
    }

    if (b16) {
        const ushort* hsrc = (const ushort*)h + (size_t)(b * NN + r0) * FF;
#pragma unroll
        for (int g0 = 0; g0 < 2; ++g0) {
            int g = t + g0 * 256;
            int row = g >> 3, c8 = (g & 7) * 8;
            uint4v u = *(const uint4v*)(hsrc + row * FF + c8);
            *(uint4v*)&aHi[SWZ(row, c8)] = u;
        }
    } else {
        const float* hsrc = (const float*)h + (size_t)(b * NN + r0) * FF;
#pragma unroll
        for (int g0 = 0; g0 < 4; ++g0) {
            int g = t + g0 * 256;
            int row = g >> 4, c4 = (g & 15) * 4;
            floatx4 x = *(const floatx4*)(hsrc + row * FF + c4);
            uint2 hi2 = { packhi(x[0], x[1]), packhi(x[2], x[3]) };
            uint2 lo2 = { packhi(x[0] - hitrunc(x[0]), x[1] - hitrunc(x[1])),
                          packhi(x[2] - hitrunc(x[2]), x[3] - hitrunc(x[3])) };
            *(uint2*)&aHi[SWZ(row, c4)] = hi2;
            *(uint2*)&aLo[SWZ(row, c4)] = lo2;
        }
    }
    __syncthreads();

    short8 ah[2], al[2];
#pragma unroll
    for (int kc = 0; kc < 2; ++kc) {
        ah[kc] = *(const short8*)&aHi[SWZ(wv * 16 + ml, kc * 32 + q * 8)];
        if (!b16) al[kc] = *(const short8*)&aLo[SWZ(wv * 16 + ml, kc * 32 + q * 8)];
    }

    floatx4 acc[4];
#pragma unroll
    for (int nt = 0; nt < 4; ++nt) {
        floatx4 a = {0.f, 0.f, 0.f, 0.f};
        if (b16) {
#pragma unroll
            for (int kc = 0; kc < 2; ++kc)
                a = __builtin_amdgcn_mfma_f32_16x16x32_bf16(ah[kc], bhf[nt][kc], a, 0, 0, 0);
        } else {
#pragma unroll
            for (int kc = 0; kc < 2; ++kc) {
                a = __builtin_amdgcn_mfma_f32_16x16x32_bf16(ah[kc], bhf[nt][kc], a, 0, 0, 0);
                a = __builtin_amdgcn_mfma_f32_16x16x32_bf16(ah[kc], blf[nt][kc], a, 0, 0, 0);
                a = __builtin_amdgcn_mfma_f32_16x16x32_bf16(al[kc], bhf[nt][kc], a, 0, 0, 0);
            }
        }
        acc[nt] = a;
    }

    // stage bf16 hp tile [row][o]
#pragma unroll
    for (int nt = 0; nt < 4; ++nt)
#pragma unroll
        for (int reg = 0; reg < 4; ++reg)
            sB[(wv * 16 + q * 4 + reg) * 72 + nt * 16 + ml] = bf16bits(acc[nt][reg]);

    float ps[4] = {0.f, 0.f, 0.f, 0.f}, pd[4] = {0.f, 0.f, 0.f, 0.f};
#pragma unroll
    for (int nt = 0; nt < 4; ++nt)
#pragma unroll
        for (int reg = 0; reg < 4; ++reg) {
            float tv = fast_tanh(acc[nt][reg]);
            ps[reg] += tv * aS[nt];
            pd[reg] += tv * aD[nt];
        }
#pragma unroll
    for (int msk = 1; msk < 16; msk <<= 1)
#pragma unroll
        for (int reg = 0; reg < 4; ++reg) {
            ps[reg] += __shfl_xor(ps[reg], msk, 64);
            pd[reg] += __shfl_xor(pd[reg], msk, 64);
        }
    if (ml == 0) {
#pragma unroll
        for (int reg = 0; reg < 4; ++reg) {
            int i = bh * NN + r0 + wv * 16 + q * 4 + reg;
            float sv = ps[reg], dv = pd[reg];
            sArr[i] = sv;
            dArr[i] = dv;
            rArr[i] = __expf(-0.8f * sv);
        }
    }
    __syncthreads();
    {   // coalesced bf16 row write: each thread stores 16 shorts (32 B) of a row
        const int row = t >> 2, cs = (t & 3) * 16;
        const ushort* sp = &sB[row * 72 + cs];
        ushort* dst = hpB + ((size_t)bh * NN + r0 + row) * 64 + cs;
        *(uint4v*)dst       = *(const uint4v*)sp;
        *(uint4v*)(dst + 8) = *(const uint4v*)(sp + 8);
    }
}

// ---- Kernel 2: rank + rowCnt + rank-ordered exp tables ----------------------
// grid 256 = 32 bh x 8 slabs; 256 thr. One 2048-iteration pass computes BOTH
// rank_j = #{K' > K_j} and cnt_i = #{m_j >= mkey(-s_i)} (same LDS stream).
// Scatters jjS[rank]=j, ehS[rank]=exp(d), elS[rank]=exp(0.2d); rowCnt[i]=cnt.
__global__ __launch_bounds__(256) void k_rank2(
    const float* __restrict__ dArr, const float* __restrict__ sArr,
    ushort* __restrict__ jjS, float* __restrict__ ehS, float* __restrict__ elS,
    int* __restrict__ rowCnt)
{
    const int bh = blockIdx.x >> 3, slab = blockIdx.x & 7, t = threadIdx.x;
    __shared__ __align__(16) unsigned long long kp[2048];
    float dOwn = 0.f;
#pragma unroll
    for (int g = 0; g < 8; ++g) {
        int jl = t + g * 256;
        float d = dArr[bh * NN + jl];
        if (g == slab) dOwn = d;
        kp[jl] = ((unsigned long long)mkey(d) << 32) | (unsigned)(2047 - jl);
    }
    const int jOwn = slab * 256 + t;
    const float sOwn = sArr[bh * NN + jOwn];
    __syncthreads();
    const unsigned long long K = kp[jOwn];
    const unsigned long long Kthr = (unsigned long long)mkey(-sOwn) << 32;
    int cr = 0, ct = 0;
#pragma unroll 8
    for (int c = 0; c < 2048; c += 4) {
        u64x2 a = *(const u64x2*)&kp[c];
        u64x2 b = *(const u64x2*)&kp[c + 2];
        cr += (a.x > K) + (a.y > K) + (b.x > K) + (b.y > K);
        ct += (a.x >= Kthr) + (a.y >= Kthr) + (b.x >= Kthr) + (b.y >= Kthr);
    }
    jjS[bh * NN + cr] = (ushort)jOwn;
    ehS[bh * NN + cr] = __expf(dOwn);
    elS[bh * NN + cr] = __expf(0.2f * dOwn);
    rowCnt[bh * NN + jOwn] = ct;
}

// ---- Kernel 3: totals + in-LDS scans + direct per-row emit ------------------
// grid 256 = 32 bh x 8 slabs of 256 rows; 512 thr = 8 waves.
// Phase B: all 64 chunk totals (8 chunks/wave; bf16 hv gathers; exp from LDS).
// Phase C: in-place chunk scans (CPre excl fwd; CSuf incl bwd; scalar twins).
// Phase D: per row (32/wave): c=cnt>>5; partial over [32c,cnt);
//          val=(CPre[c]+pe + r*(CSuf[c]-pl)) / (scalars) + bias.
__global__ __launch_bounds__(512) void k_final(
    const void* __restrict__ h,
    const ushort* __restrict__ jjS, const float* __restrict__ ehS,
    const float* __restrict__ elS, const ushort* __restrict__ hpB,
    const int* __restrict__ rowCnt, const float* __restrict__ rArr,
    const void* __restrict__ bias, void* __restrict__ out)
{
    const int bh = blockIdx.x >> 3, slab = blockIdx.x & 7;
    const int t = threadIdx.x, lane = t & 63, wv = t >> 6;

    __shared__ ushort jjL[2048];       // 4 KB
    __shared__ float ehL[2048];        // 8 KB
    __shared__ float elL[2048];        // 8 KB
    __shared__ float TehL[64][64];     // 16 KB -> CPre (excl) after scan
    __shared__ float TelL[64][64];     // 16 KB -> CSuf (incl) after scan
    __shared__ float TehSs[64], TelSs[64];
    __shared__ int sb16;
    if (t < 64) { int f = sniff_b16(h); if (t == 0) sb16 = f; }

#pragma unroll
    for (int g = 0; g < 4; ++g) {
        int x = t + g * 512;
        jjL[x] = jjS[bh * NN + x];
        ehL[x] = ehS[bh * NN + x];
        elL[x] = elS[bh * NN + x];
    }
    __syncthreads();
    const int b16 = sb16;
    const ushort* hpb = hpB + (size_t)bh * NN * FF;

    // Phase B: chunk totals (wave wv -> chunks wv*8 .. wv*8+7)
#pragma unroll 1
    for (int cc = 0; cc < 8; ++cc) {
        const int c = wv * 8 + cc;
        float teh = 0.f, tel = 0.f, tehs = 0.f, tels = 0.f;
#pragma unroll 4
        for (int u = 0; u < 32; ++u) {
            int x = c * 32 + u;
            int jj = jjL[x];
            float eh = ehL[x], el = elL[x];
            float hv = bf2f(hpb[(size_t)jj * 64 + lane]);
            teh += eh * hv; tel += el * hv; tehs += eh; tels += el;
        }
        TehL[c][lane] = teh; TelL[c][lane] = tel;
        if (lane == 0) { TehSs[c] = tehs; TelSs[c] = tels; }
    }
    __syncthreads();

    // Phase C: in-place scans
    if (wv == 0) {
        float run = 0.f;
        for (int cp = 0; cp < 64; ++cp) {
            float tv = TehL[cp][lane]; TehL[cp][lane] = run; run += tv;
        }
    } else if (wv == 1) {
        float run = 0.f;
        for (int cp = 63; cp >= 0; --cp) {
            run += TelL[cp][lane]; TelL[cp][lane] = run;
        }
    } else if (wv == 2 && lane == 0) {
        float run = 0.f;
        for (int cp = 0; cp < 64; ++cp) {
            float tv = TehSs[cp]; TehSs[cp] = run; run += tv;
        }
    } else if (wv == 3 && lane == 0) {
        float run = 0.f;
        for (int cp = 63; cp >= 0; --cp) { run += TelSs[cp]; TelSs[cp] = run; }
    }
    __syncthreads();

    // Phase D: emit 32 rows per wave
    const int i0b = slab * 256 + wv * 32;
    int cnW = 0; float rW = 0.f;
    if (lane < 32) {
        cnW = rowCnt[bh * NN + i0b + lane];
        rW  = rArr[bh * NN + i0b + lane];
    }
    const float biasv = LDIN(bias, lane, b16);
    const size_t obase = (size_t)bh * NN;

#pragma unroll 1
    for (int u = 0; u < 32; ++u) {
        const int cn = __shfl(cnW, u, 64);
        const float rr = __shfl(rW, u, 64);
        int c = cn >> 5; if (c > 63) c = 63;
        float pe = 0.f, pl = 0.f, pes = 0.f, pls = 0.f;
#pragma unroll 4
        for (int x = c * 32; x < cn; ++x) {
            int jj = jjL[x];
            float eh = ehL[x], el = elL[x];
            float hv = bf2f(hpb[(size_t)jj * 64 + lane]);
            pe += eh * hv; pl += el * hv; pes += eh; pls += el;
        }
        float num = (TehL[c][lane] + pe) + rr * (TelL[c][lane] - pl);
        float den = (TehSs[c] + pes) + rr * (TelSs[c] - pls);
        float val = num / den + biasv;
        size_t oi = (obase + i0b + u) * 64 + lane;
        if (b16) ((__hip_bfloat16*)out)[oi] = __float2bfloat16(val);
        else     ((float*)out)[oi] = val;
    }
}

extern "C" void kernel_launch(void* const* d_in, const int* in_sizes, int n_in,
                              void* d_out, int out_size, void* d_ws, size_t ws_size,
                              hipStream_t stream) {
    const void* h    = d_in[0];
    // d_in[1] = adj (bool) — unused by reference
    const void* w    = d_in[2];
    const void* asrc = d_in[3];
    const void* adst = d_in[4];
    const void* bias = d_in[5];

    float* ws = (float*)d_ws;
    ushort* hpB  = (ushort*)ws;                           // 32*2048*64 bf16 (8 MB)
    float*  sArr = ws + (size_t)BH * NN * FF / 2;         // 65536 fp32
    float*  dArr = sArr + BH * NN;
    float*  rArr = dArr + BH * NN;
    float*  ehS  = rArr + BH * NN;                        // rank-ordered
    float*  elS  = ehS + BH * NN;
    int*    rowCnt = (int*)(elS + BH * NN);               // 65536 int
    ushort* jjS  = (ushort*)(rowCnt + BH * NN);           // 65536 u16

    k_proj<<<BH * 32, 256, 0, stream>>>(h, w, asrc, adst, hpB, sArr, dArr, rArr);
    k_rank2<<<BH * 8, 256, 0, stream>>>(dArr, sArr, jjS, ehS, elS, rowCnt);
    k_final<<<BH * 8, 512, 0, stream>>>(h, jjS, ehS, elS, hpB, rowCnt, rArr,
                                        bias, d_out);
}